// Round 4
// baseline (383.845 us; speedup 1.0000x reference)
//
#include <hip/hip_runtime.h>
#include <stdint.h>

// MOLGCirculantLinear via MFMA (split-bf16), fp32 accumulate.
// x[512][1024] f32, w[128][128][8] f32, scale[64][8] f32.
// d_out = out[512][1024] ++ phase[512][128][128][8].
// Kernel1: per (b-tile of 4, gx-chunk of 16) block, 4 waves (32 gy each).
//   Per gx: D[(bb,n)][gy] = circ(x^2) . w^T  via 2x mfma_f32_32x32x16_bf16
//   (split precision: x_hi*w_hi + x_lo*w_hi + x_hi*w_lo; lo*lo dropped ~2^-16).
//   phase stored raw; poly+clamp+scale accumulated into per-lane partial out.
// Kernel2: reduce the 8 gx-chunk partials -> out = 2*sum - 128.

#define NB  512
#define NGY 128
#define NGX 128
#define NK  8
#define GXCHUNK 16
#define NCHUNK  8
#define OUTN (NB * NGY * NK)   // 524288 floats

typedef float  f32x4  __attribute__((ext_vector_type(4)));
typedef float  f32x16 __attribute__((ext_vector_type(16)));
typedef short  s16x8  __attribute__((ext_vector_type(8)));   // 8 bf16 bit-patterns

__device__ __forceinline__ void split_bf16(float v, unsigned short& h, unsigned short& l) {
    unsigned int bits = __float_as_uint(v);
    h = (unsigned short)(bits >> 16);                       // truncation split
    float hf = __uint_as_float(((unsigned int)h) << 16);
    float lo = v - hf;
    l = (unsigned short)(__float_as_uint(lo) >> 16);
}

__global__ __launch_bounds__(256, 4) void molg_mfma(
    const float* __restrict__ x,
    const float* __restrict__ w,
    const float* __restrict__ scale,
    float* __restrict__ d_out,
    float* __restrict__ part)
{
    const int lane  = threadIdx.x & 63;
    const int wv    = threadIdx.x >> 6;       // wave 0..3 -> gy tile
    const int col   = lane & 31;
    const int halfu = lane >> 5;              // k-half select (0 lower, 1 upper)

    const int chunk = blockIdx.x & (NCHUNK - 1);
    const int btile = blockIdx.x >> 3;
    const int b0    = btile * 4;
    const int gy    = (wv << 5) + col;        // B-fragment column -> gy

    const int bb_a  = col >> 3;               // A-fragment row -> (bb, n)
    const int n_a   = col & 7;

    float* phase = d_out + (size_t)OUTN;

    const float c0 = 0.02403f, c1 = -0.2699f, c2 = 1.17f,
                c3 = -2.454f,  c4 = 2.523f,  c5 = -0.08003f;

    f32x16 oacc;
#pragma unroll
    for (int i = 0; i < 16; ++i) oacc[i] = 0.f;

    for (int g = 0; g < GXCHUNK; ++g) {
        const int gx = chunk * GXCHUNK + g;

        // ---- A side: rows of circ(x^2) for this lane's (bb, n) ----
        const f32x4* xp = reinterpret_cast<const f32x4*>(
            x + (size_t)(b0 + bb_a) * 1024 + (size_t)gx * NK);
        f32x4 xa = xp[0], xb = xp[1];
        float y0 = xa[0]*xa[0], y1 = xa[1]*xa[1], y2 = xa[2]*xa[2], y3 = xa[3]*xa[3];
        float y4 = xb[0]*xb[0], y5 = xb[1]*xb[1], y6 = xb[2]*xb[2], y7 = xb[3]*xb[3];
        // u[j] = y[(-j)&7]; then rotate so z[j] = u[(j-n_a)&7] = y[(n_a-j)&7]
        float u[8] = {y0, y7, y6, y5, y4, y3, y2, y1};
        float t1[8], t2[8], z[8];
        bool r1 = (n_a & 1) != 0, r2 = (n_a & 2) != 0, r4 = (n_a & 4) != 0;
#pragma unroll
        for (int j = 0; j < 8; ++j) t1[j] = r1 ? u[(j + 7) & 7] : u[j];
#pragma unroll
        for (int j = 0; j < 8; ++j) t2[j] = r2 ? t1[(j + 6) & 7] : t1[j];
#pragma unroll
        for (int j = 0; j < 8; ++j) z[j]  = r4 ? t2[(j + 4) & 7] : t2[j];

        s16x8 a1u, a2u;
#pragma unroll
        for (int j = 0; j < 8; ++j) {
            unsigned short zh, zl;
            split_bf16(z[j], zh, zl);
            a1u[j] = (short)(halfu ? zl : zh);
            a2u[j] = (short)(halfu ? (unsigned short)0 : zh);
        }

        // ---- B side: w^T column for this lane's gy ----
        const f32x4* wp = reinterpret_cast<const f32x4*>(
            w + ((size_t)gy * NGX + gx) * NK);
        f32x4 wa = wp[0], wb = wp[1];
        float wf[8] = {wa[0], wa[1], wa[2], wa[3], wb[0], wb[1], wb[2], wb[3]};
        s16x8 b1u, b2u;
#pragma unroll
        for (int j = 0; j < 8; ++j) {
            unsigned short wh, wl;
            split_bf16(wf[j], wh, wl);
            b1u[j] = (short)wh;
            b2u[j] = (short)(halfu ? (unsigned short)0 : wl);
        }

        f32x16 zero;
#pragma unroll
        for (int i = 0; i < 16; ++i) zero[i] = 0.f;
        f32x16 acc = __builtin_amdgcn_mfma_f32_32x32x16_bf16(a1u, b1u, zero, 0, 0, 0);
        acc = __builtin_amdgcn_mfma_f32_32x32x16_bf16(a2u, b2u, acc, 0, 0, 0);

        // ---- epilogue: phase store + poly/clamp/scale accumulate ----
        const f32x4 sv = *reinterpret_cast<const f32x4*>(
            scale + (size_t)(gx & 63) * NK + 4 * halfu);

#pragma unroll
        for (int bb = 0; bb < 4; ++bb) {
            f32x4 q = {acc[4*bb + 0], acc[4*bb + 1], acc[4*bb + 2], acc[4*bb + 3]};
            f32x4* pp = reinterpret_cast<f32x4*>(
                phase + (((size_t)(b0 + bb) * NGY + gy) * NGX + gx) * NK + 4 * halfu);
            __builtin_nontemporal_store(q, pp);
#pragma unroll
            for (int qq = 0; qq < 4; ++qq) {
                float v = q[qq];
                float p = fmaf(c0, v, c1);
                p = fmaf(p, v, c2);
                p = fmaf(p, v, c3);
                p = fmaf(p, v, c4);
                p = fmaf(p, v, c5);
                p = fminf(fmaxf(p, 0.f), 1.f);
                oacc[4*bb + qq] = fmaf(p, sv[qq], oacc[4*bb + qq]);
            }
        }
    }

    // partial out for this gx-chunk
    float* pt = part + (size_t)chunk * OUTN;
#pragma unroll
    for (int bb = 0; bb < 4; ++bb) {
        f32x4 q = {oacc[4*bb + 0], oacc[4*bb + 1], oacc[4*bb + 2], oacc[4*bb + 3]};
        *reinterpret_cast<f32x4*>(
            pt + ((size_t)(b0 + bb) * NGY + gy) * NK + 4 * halfu) = q;
    }
}

__global__ __launch_bounds__(256) void molg_reduce(
    const float* __restrict__ part, float* __restrict__ out)
{
    const int i = blockIdx.x * 256 + threadIdx.x;      // f32x4 index, 131072 total
    const f32x4* p = reinterpret_cast<const f32x4*>(part);
    f32x4 s = p[i];
#pragma unroll
    for (int c = 1; c < NCHUNK; ++c) s += p[(size_t)c * (OUTN / 4) + i];
    f32x4 r;
#pragma unroll
    for (int j = 0; j < 4; ++j) r[j] = fmaf(2.f, s[j], -128.f);
    reinterpret_cast<f32x4*>(out)[i] = r;
}

extern "C" void kernel_launch(void* const* d_in, const int* in_sizes, int n_in,
                              void* d_out, int out_size, void* d_ws, size_t ws_size,
                              hipStream_t stream) {
    const float* x     = (const float*)d_in[0];
    const float* w     = (const float*)d_in[1];
    const float* scale = (const float*)d_in[2];
    float* out  = (float*)d_out;
    float* part = (float*)d_ws;   // NCHUNK * OUTN floats = 16.8 MB

    dim3 block(256);
    dim3 grid1((NB / 4) * NCHUNK);          // 1024 blocks
    hipLaunchKernelGGL(molg_mfma, grid1, block, 0, stream, x, w, scale, out, part);

    dim3 grid2(OUTN / 4 / 256);             // 512 blocks
    hipLaunchKernelGGL(molg_reduce, grid2, block, 0, stream, part, out);
}

// Round 5
// 125.162 us; speedup vs baseline: 3.0668x; 3.0668x over previous
//
#include <hip/hip_runtime.h>

// MOLGCirculantLinear: persistent-wave fused kernel.
// x[512][1024] f32, w[128][128][8] f32, scale[64][8] f32.
// d_out = out[512][1024] ++ phase[512][128][128][8].
//
// One wave per (b, 16-gy strip): 4096 waves = 1024 blocks x 256 thr = 4 blocks/CU,
// fully resident. Lane owns gx = lane and lane+64. x^2 loaded once per wave and
// reused across 16 gy; w row per gy from L2; phase streamed nontemporal;
// out reduced per gy via 3-stage butterfly + register-select + 3-stage butterfly,
// buffered per lane, stored once as two dense 256B bursts.

#define NB   512
#define NGY  128
#define NGX  128
#define NK   8
#define GYPW 16

typedef float f32x4 __attribute__((ext_vector_type(4)));

__global__ __launch_bounds__(256, 4) void molg_fused(
    const float* __restrict__ x,
    const float* __restrict__ w,
    const float* __restrict__ scale,
    float* __restrict__ d_out)
{
    const int lane = threadIdx.x & 63;
    const int wvi  = threadIdx.x >> 6;
    const int wid  = blockIdx.x * 4 + wvi;   // 0..4095
    const int b    = wid >> 3;
    const int gy0  = (wid & 7) * GYPW;

    float* out   = d_out;
    float* phase = d_out + (size_t)NB * NGY * NK;

    const float c0 = 0.02403f, c1 = -0.2699f, c2 = 1.17f,
                c3 = -2.454f,  c4 = 2.523f,  c5 = -0.08003f;

    // ---- per-wave preload: x^2 for gx=lane and gx=lane+64, scale row ----
    const f32x4* xb4 = reinterpret_cast<const f32x4*>(x + (size_t)b * 1024);
    f32x4 xa0 = xb4[2 * lane],        xa1 = xb4[2 * lane + 1];
    f32x4 xc0 = xb4[2 * (lane + 64)], xc1 = xb4[2 * (lane + 64) + 1];
    float x2a[NK] = {xa0[0]*xa0[0], xa0[1]*xa0[1], xa0[2]*xa0[2], xa0[3]*xa0[3],
                     xa1[0]*xa1[0], xa1[1]*xa1[1], xa1[2]*xa1[2], xa1[3]*xa1[3]};
    float x2b[NK] = {xc0[0]*xc0[0], xc0[1]*xc0[1], xc0[2]*xc0[2], xc0[3]*xc0[3],
                     xc1[0]*xc1[0], xc1[1]*xc1[1], xc1[2]*xc1[2], xc1[3]*xc1[3]};

    // scale[gx & 63] == scale[lane] for both gx = lane and lane+64
    const f32x4* s4 = reinterpret_cast<const f32x4*>(scale + (size_t)lane * NK);
    f32x4 sv0 = s4[0], sv1 = s4[1];
    float sv[NK] = {sv0[0], sv0[1], sv0[2], sv0[3], sv1[0], sv1[1], sv1[2], sv1[3]};

    const int l3 = (lane >> 3) & 1, l4 = (lane >> 4) & 1, l5 = (lane >> 5) & 1;
    float flo = 0.f, fhi = 0.f;

    for (int i = 0; i < GYPW; ++i) {
        const int gy = gy0 + i;
        const float* wrow = w + ((size_t)gy * NGX) * NK;
        float* prow = phase + (((size_t)b * NGY + gy) * NGX) * NK;

        float acc[NK] = {0.f, 0.f, 0.f, 0.f, 0.f, 0.f, 0.f, 0.f};

#pragma unroll
        for (int it = 0; it < 2; ++it) {
            const int gx = lane + 64 * it;
            const f32x4* w4 = reinterpret_cast<const f32x4*>(wrow) + 2 * gx;
            f32x4 wa = w4[0], wb = w4[1];
            float wf[NK] = {wa[0], wa[1], wa[2], wa[3], wb[0], wb[1], wb[2], wb[3]};
            const float* x2 = it ? x2b : x2a;

            float xr[NK];
#pragma unroll
            for (int n = 0; n < NK; ++n) {
                float s = 0.f;
#pragma unroll
                for (int m = 0; m < NK; ++m)
                    s = fmaf(wf[m], x2[(n - m) & 7], s);
                xr[n] = s;
            }

            // phase store: 2x dwordx4 per lane (32B), nontemporal stream
            f32x4* pp = reinterpret_cast<f32x4*>(prow) + 2 * gx;
            f32x4 q0 = {xr[0], xr[1], xr[2], xr[3]};
            f32x4 q1 = {xr[4], xr[5], xr[6], xr[7]};
            __builtin_nontemporal_store(q0, pp);
            __builtin_nontemporal_store(q1, pp + 1);

            // poly -> clamp -> * scale -> accumulate
#pragma unroll
            for (int n = 0; n < NK; ++n) {
                float v = xr[n];
                float p = fmaf(c0, v, c1);
                p = fmaf(p, v, c2);
                p = fmaf(p, v, c3);
                p = fmaf(p, v, c4);
                p = fmaf(p, v, c5);
                p = fminf(fmaxf(p, 0.f), 1.f);
                acc[n] = fmaf(p, sv[n], acc[n]);
            }
        }

        // ---- reduce acc over 64 lanes -> S[k], k=0..7 ----
        // stage A: sum over lane bits 3,4,5 (classes by lane&7)
#pragma unroll
        for (int off = 8; off <= 32; off <<= 1)
#pragma unroll
            for (int k = 0; k < NK; ++k)
                acc[k] += __shfl_xor(acc[k], off, 64);
        // select acc[(lane>>3)&7] without runtime register indexing
        float m0 = l3 ? acc[1] : acc[0];
        float m1 = l3 ? acc[3] : acc[2];
        float m2 = l3 ? acc[5] : acc[4];
        float m3 = l3 ? acc[7] : acc[6];
        float n0 = l4 ? m1 : m0;
        float n1 = l4 ? m3 : m2;
        float v  = l5 ? n1 : n0;
        // stage B: sum over lane bits 0,1,2 -> lane l holds S[l>>3]
#pragma unroll
        for (int off = 1; off <= 4; off <<= 1)
            v += __shfl_xor(v, off, 64);
        // redistribute: lane l takes S[l&7] (from lane (l&7)*8), keep if its gy
        float tmp = __shfl(v, (lane & 7) << 3, 64);
        bool mine = ((lane >> 3) == (i & 7));
        if (i < 8) flo = mine ? tmp : flo;
        else       fhi = mine ? tmp : fhi;
    }

    // out[b, (gy0+i)*8 + k]: lane = i*8+k for i<8 (flo), i-8 for fhi
    float* ob = out + (size_t)b * 1024 + gy0 * NK;
    ob[lane]      = fmaf(2.f, flo, -128.f);
    ob[lane + 64] = fmaf(2.f, fhi, -128.f);
}

extern "C" void kernel_launch(void* const* d_in, const int* in_sizes, int n_in,
                              void* d_out, int out_size, void* d_ws, size_t ws_size,
                              hipStream_t stream) {
    const float* x     = (const float*)d_in[0];
    const float* w     = (const float*)d_in[1];
    const float* scale = (const float*)d_in[2];
    float* out = (float*)d_out;

    dim3 grid(1024);   // 4096 waves: one per (b, 16-gy strip); 4 blocks/CU resident
    dim3 block(256);
    hipLaunchKernelGGL(molg_fused, grid, block, 0, stream, x, w, scale, out);
}